// Round 5
// baseline (410.735 us; speedup 1.0000x reference)
//
#include <hip/hip_runtime.h>

// Chamfer loss: B=8, V=4, N=2048, D=3 fp32.
// final = per_view[0] + sum_v per_view[v]; per_view = mean_b(cham_x + cham_y)
// => weight per (b,v,dir) job = ((v==0)?2:1)/8.
//
// R10 = R9 tiling + R7 staging cadence:
//  - pack_y pre-pass: y cols packed ONCE into MFMA frag layout (16 bf16
//    K-slots: k0-2 yh, k3-5 yl, k6-8 yh, k9-10 (wh,wl)=-0.5|y|^2 hi/lo,
//    k11-13 yl), 48B records.
//  - main: block=4 waves/128 rows; wave pair splits col-tiles by parity
//    (B-frag reuse=2). 1024 blocks; (256,3) -> 3 blocks/CU (LDS 50.7KB).
//  - staging: CHUNK=512 cols (24KB), double-buffered, REG-staged (T14:
//    6 float4 loads at chunk top, 6 ds_write_b128 after compute) -- one
//    barrier per ~520 issue-cycles, load latency compute-hidden.
//    (R9's global_load_lds + 256-col chunks exposed DMA latency at every
//    barrier: vmcnt(0) drain every ~240 cycles -> 38us. Reverted.)

#define B_ 8
#define V_ 4
#define N_ 2048
#define JOBS 64
#define RPB 128                        // rows per block
#define GRID_ (JOBS * (N_ / RPB))      // 1024 blocks
#define CHUNK 512                      // cols per LDS chunk
#define NCHUNK (N_ / CHUNK)            // 4
#define CPITCH 24                      // ushorts per packed col (48 B)
#define CHV4 (CHUNK * CPITCH / 8)      // float4 per chunk = 1536

typedef short bf16x8 __attribute__((ext_vector_type(8)));
typedef float f32x16 __attribute__((ext_vector_type(16)));

__device__ __forceinline__ unsigned short f2bf(float f) {
  union { float f; unsigned u; } v; v.f = f;
  const unsigned r = v.u + 0x7fffu + ((v.u >> 16) & 1u);  // RNE
  return (unsigned short)(r >> 16);
}
__device__ __forceinline__ float bf2f(unsigned short h) {
  union { unsigned u; float f; } v; v.u = ((unsigned)h) << 16;
  return v.f;
}

__device__ __forceinline__ void pack_col(float y0, float y1, float y2,
                                         unsigned short* dst) {
  const unsigned short h0 = f2bf(y0), h1 = f2bf(y1), h2 = f2bf(y2);
  const unsigned short l0 = f2bf(y0 - bf2f(h0));
  const unsigned short l1 = f2bf(y1 - bf2f(h1));
  const unsigned short l2 = f2bf(y2 - bf2f(h2));
  const float w = -0.5f * fmaf(y0, y0, fmaf(y1, y1, y2 * y2));
  const unsigned short wh = f2bf(w);
  const unsigned short wl = f2bf(w - bf2f(wh));
  bf16x8 b0, b1;
  b0[0] = (short)h0; b0[1] = (short)h1; b0[2] = (short)h2;   // k0-2
  b0[3] = (short)l0; b0[4] = (short)l1; b0[5] = (short)l2;   // k3-5
  b0[6] = (short)h0; b0[7] = (short)h1;                      // k6-7
  b1[0] = (short)h2;                                         // k8
  b1[1] = (short)wh; b1[2] = (short)wl;                      // k9-10
  b1[3] = (short)l0; b1[4] = (short)l1; b1[5] = (short)l2;   // k11-13
  b1[6] = 0; b1[7] = 0;                                      // k14-15
  *(bf16x8*)(dst) = b0;
  *(bf16x8*)(dst + 8) = b1;
}

// Pack all 64 (pair, src) y-panels: panel even = X data, odd = T data.
__global__ __launch_bounds__(256) void pack_y(
    const float* __restrict__ X, const float* __restrict__ T,
    unsigned short* __restrict__ P) {
  const int tid = blockIdx.x * 256 + threadIdx.x;   // [0, 131072)
  const int panel = tid >> 11;
  const int col = tid & (N_ - 1);
  const int pair = panel >> 1;
  const float* src = ((panel & 1) ? T : X) + (size_t)pair * N_ * 3 + col * 3;
  pack_col(src[0], src[1], src[2], P + (size_t)tid * CPITCH);
}

__global__ __launch_bounds__(256, 3) void chamfer_main(
    const float* __restrict__ X, const float* __restrict__ T,
    const unsigned short* __restrict__ P, float* __restrict__ bsum) {
  __shared__ unsigned short yf[2][CHUNK * CPITCH];  // 2 x 24 KB
  __shared__ float redrow[4][64];
  __shared__ float redxn[2][64];
  __shared__ float red4[4];

  // XCD swizzle: physical p -> XCD p&7; XCD x owns 128 logical bids = 8 jobs.
  const int p = blockIdx.x;
  const int bid = (p & 7) * (GRID_ / 8) + (p >> 3);
  const int job = bid >> 4;          // [0,64): 16 blocks per job
  const int rc  = bid & 15;          // row-chunk of 128
  const int pair = job >> 1;
  const int dir  = job & 1;          // 0: rows=X cols=T (cham_x), 1: swapped
  const float* xb = (dir ? T : X) + (size_t)pair * N_ * 3;
  const unsigned short* Pb =
      P + ((size_t)((pair << 1) | (dir ^ 1))) * N_ * CPITCH;  // y frag panel
  const int t = threadIdx.x;
  const int lane = t & 63;
  const int wv = t >> 6;
  const int lr = lane & 31;          // A-row / B-col within tile
  const int g  = lane >> 5;          // K-group
  const int rowhalf = wv >> 1;       // which 64-row half of the block
  const int parity  = wv & 1;        // which col-tile parity this wave owns

  // ---- A fragments: 2 row-tiles of 32 (shared by the wave pair) ----
  bf16x8 afrag[2];
  float xn2[2];
  const int rbase = rc * RPB + rowhalf * 64;
#pragma unroll
  for (int rt = 0; rt < 2; ++rt) {
    const int r = rbase + rt * 32 + lr;
    const float x0 = xb[r * 3 + 0], x1 = xb[r * 3 + 1], x2 = xb[r * 3 + 2];
    xn2[rt] = fmaf(x0, x0, fmaf(x1, x1, x2 * x2));
    const unsigned short h0 = f2bf(x0), h1 = f2bf(x1), h2 = f2bf(x2);
    const unsigned short l0 = f2bf(x0 - bf2f(h0));
    const unsigned short l1 = f2bf(x1 - bf2f(h1));
    const unsigned short l2 = f2bf(x2 - bf2f(h2));
    const unsigned short ONE = 0x3F80;  // bf16 1.0
    bf16x8 a;
    if (g == 0) {
      a[0] = (short)h0; a[1] = (short)h1; a[2] = (short)h2;
      a[3] = (short)h0; a[4] = (short)h1; a[5] = (short)h2;
      a[6] = (short)l0; a[7] = (short)l1;
    } else {
      a[0] = (short)l2; a[1] = (short)ONE; a[2] = (short)ONE;
      a[3] = (short)l0; a[4] = (short)l1; a[5] = (short)l2;
      a[6] = 0; a[7] = 0;
    }
    afrag[rt] = a;
  }

  f32x16 r0, r1;
#pragma unroll
  for (int j = 0; j < 16; ++j) { r0[j] = -1e30f; r1[j] = -1e30f; }

  const float4* Pv = (const float4*)Pb;
  // ---- stage chunk 0 (reg-staged linear copy, conflict-free b128 writes) ----
  {
    float4* dst = (float4*)yf[0];
#pragma unroll
    for (int k = 0; k < 6; ++k) dst[t + k * 256] = Pv[t + k * 256];
  }
  __syncthreads();

#pragma unroll 2
  for (int ch = 0; ch < NCHUNK; ++ch) {
    // T14: issue next-chunk loads early; ds_write late (after compute).
    float4 s0, s1, s2, s3, s4, s5;
    if (ch + 1 < NCHUNK) {
      const float4* src = Pv + (ch + 1) * CHV4;
      s0 = src[t];           s1 = src[t + 256];  s2 = src[t + 512];
      s3 = src[t + 768];     s4 = src[t + 1024]; s5 = src[t + 1280];
    }
    const unsigned short* bufb = yf[ch & 1];
    // my col-tiles this chunk: parity half of 16 tiles, as 4 (bA,bB) pairs
#pragma unroll
    for (int pp = 0; pp < 4; ++pp) {
      const unsigned short* pa =
          bufb + (size_t)((pp * 4 + parity) * 32 + lr) * CPITCH + g * 8;
      const bf16x8 bA = *(const bf16x8*)pa;                   // ds_read_b128
      const bf16x8 bB = *(const bf16x8*)(pa + 2 * 32 * CPITCH);
      const f32x16 d00 =
          __builtin_amdgcn_mfma_f32_32x32x16_bf16(afrag[0], bA, (f32x16){}, 0, 0, 0);
      const f32x16 d01 =
          __builtin_amdgcn_mfma_f32_32x32x16_bf16(afrag[0], bB, (f32x16){}, 0, 0, 0);
#pragma unroll
      for (int j = 0; j < 16; ++j) r0[j] = fmaxf(fmaxf(r0[j], d00[j]), d01[j]);
      const f32x16 d10 =
          __builtin_amdgcn_mfma_f32_32x32x16_bf16(afrag[1], bA, (f32x16){}, 0, 0, 0);
      const f32x16 d11 =
          __builtin_amdgcn_mfma_f32_32x32x16_bf16(afrag[1], bB, (f32x16){}, 0, 0, 0);
#pragma unroll
      for (int j = 0; j < 16; ++j) r1[j] = fmaxf(fmaxf(r1[j], d10[j]), d11[j]);
    }
    if (ch + 1 < NCHUNK) {   // write-late into the other buffer
      float4* dst = (float4*)yf[(ch + 1) & 1];
      dst[t] = s0;          dst[t + 256] = s1;   dst[t + 512] = s2;
      dst[t + 768] = s3;    dst[t + 1024] = s4;  dst[t + 1280] = s5;
    }
    __syncthreads();  // writes visible; reads of current done before overwrite
  }

  // ---- tail: butterfly row-max (this wave's parity cols), cross-wave merge.
  // C layout: col=lane&31, row=(j&3)+8*(j>>2)+4*(lane>>5).
#pragma unroll
  for (int rt = 0; rt < 2; ++rt) {
#pragma unroll
    for (int j = 0; j < 16; ++j) {
      float m = rt ? r1[j] : r0[j];
      m = fmaxf(m, __shfl_xor(m, 1, 64));
      m = fmaxf(m, __shfl_xor(m, 2, 64));
      m = fmaxf(m, __shfl_xor(m, 4, 64));
      m = fmaxf(m, __shfl_xor(m, 8, 64));
      m = fmaxf(m, __shfl_xor(m, 16, 64));   // allreduce over 32 lr-lanes
      const int rl = (j & 3) + 8 * (j >> 2) + 4 * g;
      if (lr == rl) {
        redrow[wv][rt * 32 + rl] = m;
        if (!parity) redxn[rowhalf][rt * 32 + rl] = xn2[rt];
      }
    }
  }
  __syncthreads();

  float d = 0.0f;
  if (t < 128) {                      // one thread per row of the block
    const int wp = t >> 6, q = t & 63;
    const float mx = fmaxf(redrow[2 * wp][q], redrow[2 * wp + 1][q]);
    d = fmaf(-2.0f, mx, redxn[wp][q]);
  }
  const int v_ = pair & (V_ - 1);
  float acc = d * (((v_ == 0) ? 2.0f : 1.0f) * (1.0f / (float)B_));
#pragma unroll
  for (int o = 32; o > 0; o >>= 1) acc += __shfl_down(acc, o, 64);
  if (lane == 0) red4[wv] = acc;
  __syncthreads();
  if (t == 0) bsum[bid] = (red4[0] + red4[1]) + (red4[2] + red4[3]);
}

__global__ __launch_bounds__(256) void chamfer_final(
    const float* __restrict__ bsum, float* __restrict__ out) {
  __shared__ float red4[4];
  const int t = threadIdx.x;
  float v = (bsum[t] + bsum[t + 256]) + (bsum[t + 512] + bsum[t + 768]);
#pragma unroll
  for (int o = 32; o > 0; o >>= 1) v += __shfl_down(v, o, 64);
  const int lane = t & 63, wid = t >> 6;
  if (lane == 0) red4[wid] = v;
  __syncthreads();
  if (t == 0) out[0] = (red4[0] + red4[1]) + (red4[2] + red4[3]);
}

extern "C" void kernel_launch(void* const* d_in, const int* in_sizes, int n_in,
                              void* d_out, int out_size, void* d_ws, size_t ws_size,
                              hipStream_t stream) {
  const float* X = (const float*)d_in[0];
  const float* T = (const float*)d_in[1];
  float* out = (float*)d_out;
  unsigned short* P = (unsigned short*)d_ws;            // 64*2048*48B = 6 MB
  float* bsum = (float*)((char*)d_ws + (size_t)JOBS * N_ * CPITCH * 2);  // 1024 f

  pack_y<<<(JOBS * N_) / 256, 256, 0, stream>>>(X, T, P);
  chamfer_main<<<GRID_, 256, 0, stream>>>(X, T, P, bsum);
  chamfer_final<<<1, 256, 0, stream>>>(bsum, out);
}

// Round 6
// 239.406 us; speedup vs baseline: 1.7156x; 1.7156x over previous
//
#include <hip/hip_runtime.h>

// Chamfer loss: B=8, V=4, N=2048, D=3 fp32.
// final = per_view[0] + sum_v per_view[v]; per_view = mean_b(cham_x + cham_y)
// => weight per (b,v,dir) job = ((v==0)?2:1)/8.
//
// R11 = R10 with launch_bounds(256,2) — the register-budget fix.
// R8 (cap 128) and R10 (cap ~170) both AGPR-spilled ~1.4GB of scratch: the
// unrolled chunk body keeps up to 8 MFMA d-tiles (128 regs) + 32 acc live.
// (256,2) = 256-reg budget, proven fit by R7. Occupancy 2 blocks/CU resident.
//  - pack_y pre-pass: y cols packed ONCE into MFMA frag layout (16 bf16
//    K-slots: k0-2 yh, k3-5 yl, k6-8 yh, k9-10 (wh,wl)=-0.5|y|^2 hi/lo,
//    k11-13 yl), 48B records.
//  - main: block=4 waves/128 rows; wave pair splits col-tiles by parity
//    (B-frag reuse=2). 1024 blocks.
//  - staging: CHUNK=512 cols (24KB), double-buffered, REG-staged (T14:
//    6 float4 loads at chunk top, 6 ds_write_b128 after compute) -- one
//    barrier per ~520 issue-cycles, load latency compute-hidden.

#define B_ 8
#define V_ 4
#define N_ 2048
#define JOBS 64
#define RPB 128                        // rows per block
#define GRID_ (JOBS * (N_ / RPB))      // 1024 blocks
#define CHUNK 512                      // cols per LDS chunk
#define NCHUNK (N_ / CHUNK)            // 4
#define CPITCH 24                      // ushorts per packed col (48 B)
#define CHV4 (CHUNK * CPITCH / 8)      // float4 per chunk = 1536

typedef short bf16x8 __attribute__((ext_vector_type(8)));
typedef float f32x16 __attribute__((ext_vector_type(16)));

__device__ __forceinline__ unsigned short f2bf(float f) {
  union { float f; unsigned u; } v; v.f = f;
  const unsigned r = v.u + 0x7fffu + ((v.u >> 16) & 1u);  // RNE
  return (unsigned short)(r >> 16);
}
__device__ __forceinline__ float bf2f(unsigned short h) {
  union { unsigned u; float f; } v; v.u = ((unsigned)h) << 16;
  return v.f;
}

__device__ __forceinline__ void pack_col(float y0, float y1, float y2,
                                         unsigned short* dst) {
  const unsigned short h0 = f2bf(y0), h1 = f2bf(y1), h2 = f2bf(y2);
  const unsigned short l0 = f2bf(y0 - bf2f(h0));
  const unsigned short l1 = f2bf(y1 - bf2f(h1));
  const unsigned short l2 = f2bf(y2 - bf2f(h2));
  const float w = -0.5f * fmaf(y0, y0, fmaf(y1, y1, y2 * y2));
  const unsigned short wh = f2bf(w);
  const unsigned short wl = f2bf(w - bf2f(wh));
  bf16x8 b0, b1;
  b0[0] = (short)h0; b0[1] = (short)h1; b0[2] = (short)h2;   // k0-2
  b0[3] = (short)l0; b0[4] = (short)l1; b0[5] = (short)l2;   // k3-5
  b0[6] = (short)h0; b0[7] = (short)h1;                      // k6-7
  b1[0] = (short)h2;                                         // k8
  b1[1] = (short)wh; b1[2] = (short)wl;                      // k9-10
  b1[3] = (short)l0; b1[4] = (short)l1; b1[5] = (short)l2;   // k11-13
  b1[6] = 0; b1[7] = 0;                                      // k14-15
  *(bf16x8*)(dst) = b0;
  *(bf16x8*)(dst + 8) = b1;
}

// Pack all 64 (pair, src) y-panels: panel even = X data, odd = T data.
__global__ __launch_bounds__(256) void pack_y(
    const float* __restrict__ X, const float* __restrict__ T,
    unsigned short* __restrict__ P) {
  const int tid = blockIdx.x * 256 + threadIdx.x;   // [0, 131072)
  const int panel = tid >> 11;
  const int col = tid & (N_ - 1);
  const int pair = panel >> 1;
  const float* src = ((panel & 1) ? T : X) + (size_t)pair * N_ * 3 + col * 3;
  pack_col(src[0], src[1], src[2], P + (size_t)tid * CPITCH);
}

__global__ __launch_bounds__(256, 2) void chamfer_main(
    const float* __restrict__ X, const float* __restrict__ T,
    const unsigned short* __restrict__ P, float* __restrict__ bsum) {
  __shared__ unsigned short yf[2][CHUNK * CPITCH];  // 2 x 24 KB
  __shared__ float redrow[4][64];
  __shared__ float redxn[2][64];
  __shared__ float red4[4];

  // XCD swizzle: physical p -> XCD p&7; XCD x owns 128 logical bids = 8 jobs.
  const int p = blockIdx.x;
  const int bid = (p & 7) * (GRID_ / 8) + (p >> 3);
  const int job = bid >> 4;          // [0,64): 16 blocks per job
  const int rc  = bid & 15;          // row-chunk of 128
  const int pair = job >> 1;
  const int dir  = job & 1;          // 0: rows=X cols=T (cham_x), 1: swapped
  const float* xb = (dir ? T : X) + (size_t)pair * N_ * 3;
  const unsigned short* Pb =
      P + ((size_t)((pair << 1) | (dir ^ 1))) * N_ * CPITCH;  // y frag panel
  const int t = threadIdx.x;
  const int lane = t & 63;
  const int wv = t >> 6;
  const int lr = lane & 31;          // A-row / B-col within tile
  const int g  = lane >> 5;          // K-group
  const int rowhalf = wv >> 1;       // which 64-row half of the block
  const int parity  = wv & 1;        // which col-tile parity this wave owns

  // ---- A fragments: 2 row-tiles of 32 (shared by the wave pair) ----
  bf16x8 afrag[2];
  float xn2[2];
  const int rbase = rc * RPB + rowhalf * 64;
#pragma unroll
  for (int rt = 0; rt < 2; ++rt) {
    const int r = rbase + rt * 32 + lr;
    const float x0 = xb[r * 3 + 0], x1 = xb[r * 3 + 1], x2 = xb[r * 3 + 2];
    xn2[rt] = fmaf(x0, x0, fmaf(x1, x1, x2 * x2));
    const unsigned short h0 = f2bf(x0), h1 = f2bf(x1), h2 = f2bf(x2);
    const unsigned short l0 = f2bf(x0 - bf2f(h0));
    const unsigned short l1 = f2bf(x1 - bf2f(h1));
    const unsigned short l2 = f2bf(x2 - bf2f(h2));
    const unsigned short ONE = 0x3F80;  // bf16 1.0
    bf16x8 a;
    if (g == 0) {
      a[0] = (short)h0; a[1] = (short)h1; a[2] = (short)h2;
      a[3] = (short)h0; a[4] = (short)h1; a[5] = (short)h2;
      a[6] = (short)l0; a[7] = (short)l1;
    } else {
      a[0] = (short)l2; a[1] = (short)ONE; a[2] = (short)ONE;
      a[3] = (short)l0; a[4] = (short)l1; a[5] = (short)l2;
      a[6] = 0; a[7] = 0;
    }
    afrag[rt] = a;
  }

  f32x16 r0, r1;
#pragma unroll
  for (int j = 0; j < 16; ++j) { r0[j] = -1e30f; r1[j] = -1e30f; }

  const float4* Pv = (const float4*)Pb;
  // ---- stage chunk 0 (reg-staged linear copy, conflict-free b128 writes) ----
  {
    float4* dst = (float4*)yf[0];
#pragma unroll
    for (int k = 0; k < 6; ++k) dst[t + k * 256] = Pv[t + k * 256];
  }
  __syncthreads();

#pragma unroll 2
  for (int ch = 0; ch < NCHUNK; ++ch) {
    // T14: issue next-chunk loads early; ds_write late (after compute).
    float4 s0, s1, s2, s3, s4, s5;
    if (ch + 1 < NCHUNK) {
      const float4* src = Pv + (ch + 1) * CHV4;
      s0 = src[t];           s1 = src[t + 256];  s2 = src[t + 512];
      s3 = src[t + 768];     s4 = src[t + 1024]; s5 = src[t + 1280];
    }
    const unsigned short* bufb = yf[ch & 1];
    // my col-tiles this chunk: parity half of 16 tiles, as 4 (bA,bB) pairs
#pragma unroll
    for (int pp = 0; pp < 4; ++pp) {
      const unsigned short* pa =
          bufb + (size_t)((pp * 4 + parity) * 32 + lr) * CPITCH + g * 8;
      const bf16x8 bA = *(const bf16x8*)pa;                   // ds_read_b128
      const bf16x8 bB = *(const bf16x8*)(pa + 2 * 32 * CPITCH);
      const f32x16 d00 =
          __builtin_amdgcn_mfma_f32_32x32x16_bf16(afrag[0], bA, (f32x16){}, 0, 0, 0);
      const f32x16 d01 =
          __builtin_amdgcn_mfma_f32_32x32x16_bf16(afrag[0], bB, (f32x16){}, 0, 0, 0);
#pragma unroll
      for (int j = 0; j < 16; ++j) r0[j] = fmaxf(fmaxf(r0[j], d00[j]), d01[j]);
      const f32x16 d10 =
          __builtin_amdgcn_mfma_f32_32x32x16_bf16(afrag[1], bA, (f32x16){}, 0, 0, 0);
      const f32x16 d11 =
          __builtin_amdgcn_mfma_f32_32x32x16_bf16(afrag[1], bB, (f32x16){}, 0, 0, 0);
#pragma unroll
      for (int j = 0; j < 16; ++j) r1[j] = fmaxf(fmaxf(r1[j], d10[j]), d11[j]);
    }
    if (ch + 1 < NCHUNK) {   // write-late into the other buffer
      float4* dst = (float4*)yf[(ch + 1) & 1];
      dst[t] = s0;          dst[t + 256] = s1;   dst[t + 512] = s2;
      dst[t + 768] = s3;    dst[t + 1024] = s4;  dst[t + 1280] = s5;
    }
    __syncthreads();  // writes visible; reads of current done before overwrite
  }

  // ---- tail: butterfly row-max (this wave's parity cols), cross-wave merge.
  // C layout: col=lane&31, row=(j&3)+8*(j>>2)+4*(lane>>5).
#pragma unroll
  for (int rt = 0; rt < 2; ++rt) {
#pragma unroll
    for (int j = 0; j < 16; ++j) {
      float m = rt ? r1[j] : r0[j];
      m = fmaxf(m, __shfl_xor(m, 1, 64));
      m = fmaxf(m, __shfl_xor(m, 2, 64));
      m = fmaxf(m, __shfl_xor(m, 4, 64));
      m = fmaxf(m, __shfl_xor(m, 8, 64));
      m = fmaxf(m, __shfl_xor(m, 16, 64));   // allreduce over 32 lr-lanes
      const int rl = (j & 3) + 8 * (j >> 2) + 4 * g;
      if (lr == rl) {
        redrow[wv][rt * 32 + rl] = m;
        if (!parity) redxn[rowhalf][rt * 32 + rl] = xn2[rt];
      }
    }
  }
  __syncthreads();

  float d = 0.0f;
  if (t < 128) {                      // one thread per row of the block
    const int wp = t >> 6, q = t & 63;
    const float mx = fmaxf(redrow[2 * wp][q], redrow[2 * wp + 1][q]);
    d = fmaf(-2.0f, mx, redxn[wp][q]);
  }
  const int v_ = pair & (V_ - 1);
  float acc = d * (((v_ == 0) ? 2.0f : 1.0f) * (1.0f / (float)B_));
#pragma unroll
  for (int o = 32; o > 0; o >>= 1) acc += __shfl_down(acc, o, 64);
  if (lane == 0) red4[wv] = acc;
  __syncthreads();
  if (t == 0) bsum[bid] = (red4[0] + red4[1]) + (red4[2] + red4[3]);
}

__global__ __launch_bounds__(256) void chamfer_final(
    const float* __restrict__ bsum, float* __restrict__ out) {
  __shared__ float red4[4];
  const int t = threadIdx.x;
  float v = (bsum[t] + bsum[t + 256]) + (bsum[t + 512] + bsum[t + 768]);
#pragma unroll
  for (int o = 32; o > 0; o >>= 1) v += __shfl_down(v, o, 64);
  const int lane = t & 63, wid = t >> 6;
  if (lane == 0) red4[wid] = v;
  __syncthreads();
  if (t == 0) out[0] = (red4[0] + red4[1]) + (red4[2] + red4[3]);
}

extern "C" void kernel_launch(void* const* d_in, const int* in_sizes, int n_in,
                              void* d_out, int out_size, void* d_ws, size_t ws_size,
                              hipStream_t stream) {
  const float* X = (const float*)d_in[0];
  const float* T = (const float*)d_in[1];
  float* out = (float*)d_out;
  unsigned short* P = (unsigned short*)d_ws;            // 64*2048*48B = 6 MB
  float* bsum = (float*)((char*)d_ws + (size_t)JOBS * N_ * CPITCH * 2);  // 1024 f

  pack_y<<<(JOBS * N_) / 256, 256, 0, stream>>>(X, T, P);
  chamfer_main<<<GRID_, 256, 0, stream>>>(X, T, P, bsum);
  chamfer_final<<<1, 256, 0, stream>>>(bsum, out);
}

// Round 7
// 26.671 us; speedup vs baseline: 15.3999x; 8.9762x over previous
//
#include <hip/hip_runtime.h>

// Chamfer loss: B=8, V=4, N=2048, D=3 fp32.
// final = per_view[0] + sum_v per_view[v]; per_view = mean_b(cham_x + cham_y)
// => weight per (b,v,dir) job = ((v==0)?2:1)/8.
//
// R12: whole-panel-resident MFMA kernel. The packed y panel is 96KB -> fits
// LDS. 8-wave block stages it ONCE (global_load_lds x12/thread), then the
// main loop is barrier-free: ds_read_b128 -> 4x mfma_32x32x16_bf16 -> 32x
// v_max3, no staging regs alive, no chunk double-buffer. This kills the
// AGPR-spill that plagued R8/R10/R11 (chunked dbuf staging + 8 hoisted
// d-tiles + 32-reg acc > budget -> 0.75-1.4GB scratch traffic).
// dot(x,y) via 4-term bf16 split inside one K=16 MFMA; -0.5|y|^2 folded in
// as (wh,wl) K-slots vs A=1.0. t = x.y-0.5|y|^2; min d2 <=> max t;
// d2 = |x|^2-2t with |x|^2 fp32. K-slot map (A and B share it):
//  k0-2 xh*yh  k3-5 xh*yl  k6-8 xl*yh  k9-10 1*(wh,wl)  k11-13 xl*yl.
// Grid 256 = 1 block/CU; wave owns 64 rows (complete row-max in-wave).

#define B_ 8
#define V_ 4
#define N_ 2048
#define JOBS 64
#define RPB 512                        // rows per block (8 waves x 64)
#define GRID_ (JOBS * (N_ / RPB))      // 256 blocks
#define CPITCH 24                      // ushorts per packed col (48 B)
#define PANEL_BYTES (N_ * CPITCH * 2)  // 98304 B

typedef short bf16x8 __attribute__((ext_vector_type(8)));
typedef float f32x16 __attribute__((ext_vector_type(16)));

__device__ __forceinline__ unsigned short f2bf(float f) {
  union { float f; unsigned u; } v; v.f = f;
  const unsigned r = v.u + 0x7fffu + ((v.u >> 16) & 1u);  // RNE
  return (unsigned short)(r >> 16);
}
__device__ __forceinline__ float bf2f(unsigned short h) {
  union { unsigned u; float f; } v; v.u = ((unsigned)h) << 16;
  return v.f;
}

__device__ __forceinline__ void pack_col(float y0, float y1, float y2,
                                         unsigned short* dst) {
  const unsigned short h0 = f2bf(y0), h1 = f2bf(y1), h2 = f2bf(y2);
  const unsigned short l0 = f2bf(y0 - bf2f(h0));
  const unsigned short l1 = f2bf(y1 - bf2f(h1));
  const unsigned short l2 = f2bf(y2 - bf2f(h2));
  const float w = -0.5f * fmaf(y0, y0, fmaf(y1, y1, y2 * y2));
  const unsigned short wh = f2bf(w);
  const unsigned short wl = f2bf(w - bf2f(wh));
  bf16x8 b0, b1;
  b0[0] = (short)h0; b0[1] = (short)h1; b0[2] = (short)h2;   // k0-2
  b0[3] = (short)l0; b0[4] = (short)l1; b0[5] = (short)l2;   // k3-5
  b0[6] = (short)h0; b0[7] = (short)h1;                      // k6-7
  b1[0] = (short)h2;                                         // k8
  b1[1] = (short)wh; b1[2] = (short)wl;                      // k9-10
  b1[3] = (short)l0; b1[4] = (short)l1; b1[5] = (short)l2;   // k11-13
  b1[6] = 0; b1[7] = 0;                                      // k14-15
  *(bf16x8*)(dst) = b0;
  *(bf16x8*)(dst + 8) = b1;
}

// Pack all 64 (pair, src) y-panels: panel even = X data, odd = T data.
__global__ __launch_bounds__(256) void pack_y(
    const float* __restrict__ X, const float* __restrict__ T,
    unsigned short* __restrict__ P) {
  const int tid = blockIdx.x * 256 + threadIdx.x;   // [0, 131072)
  const int panel = tid >> 11;
  const int col = tid & (N_ - 1);
  const int pair = panel >> 1;
  const float* src = ((panel & 1) ? T : X) + (size_t)pair * N_ * 3 + col * 3;
  pack_col(src[0], src[1], src[2], P + (size_t)tid * CPITCH);
}

__global__ __launch_bounds__(512, 2) void chamfer_main(
    const float* __restrict__ X, const float* __restrict__ T,
    const unsigned short* __restrict__ P, float* __restrict__ bsum) {
  __shared__ unsigned short yl[N_ * CPITCH];  // 96 KB: the whole packed panel
  __shared__ float red8[8];

  // XCD swizzle: physical p -> XCD p&7; XCD x owns 32 logical bids = 8 jobs.
  const int p = blockIdx.x;
  const int bid = (p & 7) * (GRID_ / 8) + (p >> 3);
  const int job = bid >> 2;          // [0,64): 4 blocks per job
  const int rc  = bid & 3;           // row-chunk of 512
  const int pair = job >> 1;
  const int dir  = job & 1;          // 0: rows=X cols=T (cham_x), 1: swapped
  const float* xb = (dir ? T : X) + (size_t)pair * N_ * 3;
  const unsigned short* Pb =
      P + ((size_t)((pair << 1) | (dir ^ 1))) * N_ * CPITCH;  // y frag panel
  const int t = threadIdx.x;
  const int lane = t & 63;
  const int wv = t >> 6;             // 8 waves
  const int lr = lane & 31;          // A-row / B-col within tile
  const int g  = lane >> 5;          // K-group (which 8 k-slots this lane feeds)

  // ---- stage the whole panel: 12 x global_load_lds_dwordx4 per thread ----
  // (linear: LDS dest = uniform base + lane*16; global src per-lane. 12KB/wave)
  {
    const char* gsrc = (const char*)Pb + wv * 12288 + lane * 16;
    char* ldst = (char*)yl + wv * 12288;
#pragma unroll
    for (int i = 0; i < 12; ++i) {
      __builtin_amdgcn_global_load_lds(
          (const __attribute__((address_space(1))) unsigned int*)(gsrc + i * 1024),
          (__attribute__((address_space(3))) unsigned int*)(ldst + i * 1024),
          16, 0, 0);
    }
  }

  // ---- A fragments (overlaps with DMA): wave owns 64 rows = 2 tiles ----
  bf16x8 afrag[2];
  float xn2[2];
  const int rbase = rc * RPB + wv * 64;
#pragma unroll
  for (int rt = 0; rt < 2; ++rt) {
    const int r = rbase + rt * 32 + lr;
    const float x0 = xb[r * 3 + 0], x1 = xb[r * 3 + 1], x2 = xb[r * 3 + 2];
    xn2[rt] = fmaf(x0, x0, fmaf(x1, x1, x2 * x2));
    const unsigned short h0 = f2bf(x0), h1 = f2bf(x1), h2 = f2bf(x2);
    const unsigned short l0 = f2bf(x0 - bf2f(h0));
    const unsigned short l1 = f2bf(x1 - bf2f(h1));
    const unsigned short l2 = f2bf(x2 - bf2f(h2));
    const unsigned short ONE = 0x3F80;  // bf16 1.0
    bf16x8 a;
    if (g == 0) {  // k0-7
      a[0] = (short)h0; a[1] = (short)h1; a[2] = (short)h2;
      a[3] = (short)h0; a[4] = (short)h1; a[5] = (short)h2;
      a[6] = (short)l0; a[7] = (short)l1;
    } else {       // k8-15
      a[0] = (short)l2; a[1] = (short)ONE; a[2] = (short)ONE;
      a[3] = (short)l0; a[4] = (short)l1; a[5] = (short)l2;
      a[6] = 0; a[7] = 0;
    }
    afrag[rt] = a;
  }

  f32x16 r0, r1;
#pragma unroll
  for (int j = 0; j < 16; ++j) { r0[j] = -1e30f; r1[j] = -1e30f; }

  __syncthreads();  // panel resident (barrier drains vmcnt); no more barriers

  // ---- main loop: 32 col-tile pairs, barrier-free, read-only LDS ----
  // 48B record pitch => wave64 b128 read is bank-conflict-free (verified
  // SQ_LDS_BANK_CONFLICT=0 in R10/R11 with identical pattern).
#pragma unroll 4
  for (int ct = 0; ct < 32; ++ct) {
    const unsigned short* pa = yl + (size_t)(ct * 64 + lr) * CPITCH + g * 8;
    const bf16x8 bA = *(const bf16x8*)pa;                    // ds_read_b128
    const bf16x8 bB = *(const bf16x8*)(pa + 32 * CPITCH);
    const f32x16 d00 =
        __builtin_amdgcn_mfma_f32_32x32x16_bf16(afrag[0], bA, (f32x16){}, 0, 0, 0);
    const f32x16 d01 =
        __builtin_amdgcn_mfma_f32_32x32x16_bf16(afrag[0], bB, (f32x16){}, 0, 0, 0);
    const f32x16 d10 =
        __builtin_amdgcn_mfma_f32_32x32x16_bf16(afrag[1], bA, (f32x16){}, 0, 0, 0);
    const f32x16 d11 =
        __builtin_amdgcn_mfma_f32_32x32x16_bf16(afrag[1], bB, (f32x16){}, 0, 0, 0);
#pragma unroll
    for (int j = 0; j < 16; ++j) {   // 2 new values per v_max3
      r0[j] = fmaxf(fmaxf(r0[j], d00[j]), d01[j]);
      r1[j] = fmaxf(fmaxf(r1[j], d10[j]), d11[j]);
    }
  }

  // ---- tail: in-wave butterfly row-max (cols complete), weighted sum ----
  // C layout: col=lane&31, row=(j&3)+8*(j>>2)+4*(lane>>5).
  float acc = 0.0f;
#pragma unroll
  for (int rt = 0; rt < 2; ++rt) {
#pragma unroll
    for (int j = 0; j < 16; ++j) {
      float m = rt ? r1[j] : r0[j];
      m = fmaxf(m, __shfl_xor(m, 1, 64));
      m = fmaxf(m, __shfl_xor(m, 2, 64));
      m = fmaxf(m, __shfl_xor(m, 4, 64));
      m = fmaxf(m, __shfl_xor(m, 8, 64));
      m = fmaxf(m, __shfl_xor(m, 16, 64));   // allreduce over 32 lr-lanes
      const int rl = (j & 3) + 8 * (j >> 2) + 4 * g;
      if (lr == rl) acc += fmaf(-2.0f, m, xn2[rt]);  // owner adds min-d2
    }
  }
  const int v_ = pair & (V_ - 1);
  acc *= ((v_ == 0) ? 2.0f : 1.0f) * (1.0f / (float)B_);
#pragma unroll
  for (int o = 32; o > 0; o >>= 1) acc += __shfl_down(acc, o, 64);
  if (lane == 0) red8[wv] = acc;
  __syncthreads();
  if (t == 0) {
    float s = 0.0f;
#pragma unroll
    for (int i = 0; i < 8; ++i) s += red8[i];
    bsum[bid] = s;
  }
}

__global__ __launch_bounds__(256) void chamfer_final(
    const float* __restrict__ bsum, float* __restrict__ out) {
  __shared__ float red4[4];
  const int t = threadIdx.x;
  float v = bsum[t];                       // 256 block sums
#pragma unroll
  for (int o = 32; o > 0; o >>= 1) v += __shfl_down(v, o, 64);
  const int lane = t & 63, wid = t >> 6;
  if (lane == 0) red4[wid] = v;
  __syncthreads();
  if (t == 0) out[0] = (red4[0] + red4[1]) + (red4[2] + red4[3]);
}

extern "C" void kernel_launch(void* const* d_in, const int* in_sizes, int n_in,
                              void* d_out, int out_size, void* d_ws, size_t ws_size,
                              hipStream_t stream) {
  const float* X = (const float*)d_in[0];
  const float* T = (const float*)d_in[1];
  float* out = (float*)d_out;
  unsigned short* P = (unsigned short*)d_ws;            // 64*2048*48B = 6 MB
  float* bsum = (float*)((char*)d_ws + (size_t)JOBS * PANEL_BYTES);  // 256 f

  pack_y<<<(JOBS * N_) / 256, 256, 0, stream>>>(X, T, P);
  chamfer_main<<<GRID_, 512, 0, stream>>>(X, T, P, bsum);
  chamfer_final<<<1, 256, 0, stream>>>(bsum, out);
}

// Round 8
// 25.606 us; speedup vs baseline: 16.0405x; 1.0416x over previous
//
#include <hip/hip_runtime.h>

// Chamfer loss: B=8, V=4, N=2048, D=3 fp32.
// final = per_view[0] + sum_v per_view[v]; per_view = mean_b(cham_x + cham_y)
// => weight per (b,v,dir) job = ((v==0)?2:1)/8.
//
// R13: 16-wave panel-resident block, 4 waves/SIMD, in-kernel pack.
// Evidence R7 vs R12: main loop is LATENCY-bound at 2 waves/SIMD (~6x pipe
// model); R6 at 4 waves/SIMD ran ~2x model. So: 1024-thr block (16 waves),
// grid 256 = 1/CU, panel packed in-kernel into 96KB LDS (no pack_y dispatch,
// no cross-XCD P traffic), waves w/w+8 share 64 rows and split col-tiles.
// Register discipline (R8/R10/R11 spill scar): cap = 128 unified regs at
// 4 waves/SIMD. unroll 1 + manual 1-deep prefetch + fold r0 before the
// d10/d11 MFMAs with a sched_barrier(0) fence => <=2 d-tiles live (32 regs)
// + r0/r1 (32) + ~45 VGPR ~= 110 < 128. No spill by construction.
//
// Math (proven R7-R12, absmax 0.0): dot(x,y) via 4-term bf16 split in one
// K=16 MFMA; -0.5|y|^2 folded as (wh,wl) K-slots vs A=1.0.
// t = x.y - 0.5|y|^2; min d2 <=> max t; d2 = |x|^2 - 2t, |x|^2 fp32.
// K-slot map (A,B share): k0-2 h*h k3-5 h*l k6-8 l*h k9-10 1*(wh,wl)
// k11-13 l*l. C layout: col=lane&31, row=(j&3)+8*(j>>2)+4*(lane>>5).

#define B_ 8
#define V_ 4
#define N_ 2048
#define JOBS 64
#define RPB 512                        // rows per block (8 row-groups x 64)
#define GRID_ (JOBS * (N_ / RPB))      // 256 blocks = 1/CU
#define CPITCH 24                      // ushorts per packed col (48 B)

typedef short bf16x8 __attribute__((ext_vector_type(8)));
typedef float f32x16 __attribute__((ext_vector_type(16)));

__device__ __forceinline__ unsigned short f2bf(float f) {
  union { float f; unsigned u; } v; v.f = f;
  const unsigned r = v.u + 0x7fffu + ((v.u >> 16) & 1u);  // RNE
  return (unsigned short)(r >> 16);
}
__device__ __forceinline__ float bf2f(unsigned short h) {
  union { unsigned u; float f; } v; v.u = ((unsigned)h) << 16;
  return v.f;
}

__device__ __forceinline__ void pack_col(float y0, float y1, float y2,
                                         unsigned short* dst) {
  const unsigned short h0 = f2bf(y0), h1 = f2bf(y1), h2 = f2bf(y2);
  const unsigned short l0 = f2bf(y0 - bf2f(h0));
  const unsigned short l1 = f2bf(y1 - bf2f(h1));
  const unsigned short l2 = f2bf(y2 - bf2f(h2));
  const float w = -0.5f * fmaf(y0, y0, fmaf(y1, y1, y2 * y2));
  const unsigned short wh = f2bf(w);
  const unsigned short wl = f2bf(w - bf2f(wh));
  bf16x8 b0, b1;
  b0[0] = (short)h0; b0[1] = (short)h1; b0[2] = (short)h2;   // k0-2
  b0[3] = (short)l0; b0[4] = (short)l1; b0[5] = (short)l2;   // k3-5
  b0[6] = (short)h0; b0[7] = (short)h1;                      // k6-7
  b1[0] = (short)h2;                                         // k8
  b1[1] = (short)wh; b1[2] = (short)wl;                      // k9-10
  b1[3] = (short)l0; b1[4] = (short)l1; b1[5] = (short)l2;   // k11-13
  b1[6] = 0; b1[7] = 0;                                      // k14-15
  *(bf16x8*)(dst) = b0;        // ds_write_b128 x2
  *(bf16x8*)(dst + 8) = b1;
}

__global__ __launch_bounds__(1024, 4) void chamfer_main(
    const float* __restrict__ X, const float* __restrict__ T,
    float* __restrict__ bsum) {
  __shared__ unsigned short yl[N_ * CPITCH];  // 96 KB packed panel
  __shared__ float redrow[16][64];            // per-wave row maxes
  __shared__ float redxn[8][64];              // |x|^2 per row
  __shared__ float red16[16];

  // XCD swizzle: physical p -> XCD p&7; XCD x owns bids [32x,32x+32) = 8 jobs.
  const int p = blockIdx.x;
  const int bid = (p & 7) * (GRID_ / 8) + (p >> 3);
  const int job = bid >> 2;          // [0,64): 4 blocks per job
  const int rc  = bid & 3;           // row-chunk of 512
  const int pair = job >> 1;
  const int dir  = job & 1;          // 0: rows=X cols=T (cham_x), 1: swapped
  const float* xb = (dir ? T : X) + (size_t)pair * N_ * 3;
  const float* yb = (dir ? X : T) + (size_t)pair * N_ * 3;
  const int t = threadIdx.x;         // 0..1023
  const int lane = t & 63;
  const int wv = t >> 6;             // 16 waves
  const int lr = lane & 31;          // A-row / B-col within tile
  const int g  = lane >> 5;          // K-group
  const int rg   = wv & 7;           // row-group (64 rows), shared by wv, wv+8
  const int half = wv >> 3;          // col half: tiles [half*32, half*32+32)

  // ---- in-kernel pack: thread t packs cols 2t, 2t+1 (one time) ----
  {
    const float2* yp2 = (const float2*)(yb + (size_t)(2 * t) * 3);  // 24B
    const float2 u0 = yp2[0], u1 = yp2[1], u2 = yp2[2];
    pack_col(u0.x, u0.y, u1.x, yl + (size_t)(2 * t) * CPITCH);
    pack_col(u1.y, u2.x, u2.y, yl + (size_t)(2 * t + 1) * CPITCH);
  }

  // ---- A fragments: row-group rg, 2 tiles of 32 (same for wv and wv+8) ----
  bf16x8 afrag[2];
  float xn2[2];
  const int rbase = rc * RPB + rg * 64;
#pragma unroll
  for (int rt = 0; rt < 2; ++rt) {
    const int r = rbase + rt * 32 + lr;
    const float x0 = xb[r * 3 + 0], x1 = xb[r * 3 + 1], x2 = xb[r * 3 + 2];
    xn2[rt] = fmaf(x0, x0, fmaf(x1, x1, x2 * x2));
    const unsigned short h0 = f2bf(x0), h1 = f2bf(x1), h2 = f2bf(x2);
    const unsigned short l0 = f2bf(x0 - bf2f(h0));
    const unsigned short l1 = f2bf(x1 - bf2f(h1));
    const unsigned short l2 = f2bf(x2 - bf2f(h2));
    const unsigned short ONE = 0x3F80;  // bf16 1.0
    bf16x8 a;
    if (g == 0) {  // k0-7
      a[0] = (short)h0; a[1] = (short)h1; a[2] = (short)h2;
      a[3] = (short)h0; a[4] = (short)h1; a[5] = (short)h2;
      a[6] = (short)l0; a[7] = (short)l1;
    } else {       // k8-15
      a[0] = (short)l2; a[1] = (short)ONE; a[2] = (short)ONE;
      a[3] = (short)l0; a[4] = (short)l1; a[5] = (short)l2;
      a[6] = 0; a[7] = 0;
    }
    afrag[rt] = a;
  }

  f32x16 r0, r1;
#pragma unroll
  for (int j = 0; j < 16; ++j) { r0[j] = -1e30f; r1[j] = -1e30f; }

  __syncthreads();  // panel packed & resident; no more barriers until tail

  // ---- main loop: 16 col-tile pairs in my half, manual 1-deep prefetch ----
  // base record: col = half*1024 + lr; 48B pitch (R10/R11: 0 bank conflicts).
  const unsigned short* basep =
      yl + (size_t)(half * 1024 + lr) * CPITCH + g * 8;
  bf16x8 cA = *(const bf16x8*)(basep);
  bf16x8 cB = *(const bf16x8*)(basep + 32 * CPITCH);
#pragma unroll 1
  for (int it = 0; it < 16; ++it) {
    const int nx = (it + 1) & 15;    // wrap: last-iter prefetch unused
    const bf16x8 nA = *(const bf16x8*)(basep + (size_t)nx * 64 * CPITCH);
    const bf16x8 nB = *(const bf16x8*)(basep + (size_t)(nx * 64 + 32) * CPITCH);
    const f32x16 d00 =
        __builtin_amdgcn_mfma_f32_32x32x16_bf16(afrag[0], cA, (f32x16){}, 0, 0, 0);
    const f32x16 d01 =
        __builtin_amdgcn_mfma_f32_32x32x16_bf16(afrag[0], cB, (f32x16){}, 0, 0, 0);
#pragma unroll
    for (int j = 0; j < 16; ++j) r0[j] = fmaxf(fmaxf(r0[j], d00[j]), d01[j]);
    __builtin_amdgcn_sched_barrier(0);  // fence: d00/d01 dead before d10/d11
    const f32x16 d10 =
        __builtin_amdgcn_mfma_f32_32x32x16_bf16(afrag[1], cA, (f32x16){}, 0, 0, 0);
    const f32x16 d11 =
        __builtin_amdgcn_mfma_f32_32x32x16_bf16(afrag[1], cB, (f32x16){}, 0, 0, 0);
#pragma unroll
    for (int j = 0; j < 16; ++j) r1[j] = fmaxf(fmaxf(r1[j], d10[j]), d11[j]);
    cA = nA;
    cB = nB;
  }

  // ---- tail: butterfly row-max over my 32 cols, cross-wave merge ----
#pragma unroll
  for (int rt = 0; rt < 2; ++rt) {
#pragma unroll
    for (int j = 0; j < 16; ++j) {
      float m = rt ? r1[j] : r0[j];
      m = fmaxf(m, __shfl_xor(m, 1, 64));
      m = fmaxf(m, __shfl_xor(m, 2, 64));
      m = fmaxf(m, __shfl_xor(m, 4, 64));
      m = fmaxf(m, __shfl_xor(m, 8, 64));
      m = fmaxf(m, __shfl_xor(m, 16, 64));   // allreduce over 32 lr-lanes
      const int rl = (j & 3) + 8 * (j >> 2) + 4 * g;
      if (lr == rl) {
        redrow[wv][rt * 32 + rl] = m;
        if (wv < 8) redxn[rg][rt * 32 + rl] = xn2[rt];
      }
    }
  }
  __syncthreads();

  float d = 0.0f;
  if (t < 512) {                      // one thread per row of the block
    const int g2 = t >> 6, q = t & 63;
    const float mx = fmaxf(redrow[g2][q], redrow[g2 + 8][q]);
    d = fmaf(-2.0f, mx, redxn[g2][q]);
  }
  const int v_ = pair & (V_ - 1);
  float acc = d * (((v_ == 0) ? 2.0f : 1.0f) * (1.0f / (float)B_));
#pragma unroll
  for (int o = 32; o > 0; o >>= 1) acc += __shfl_down(acc, o, 64);
  if (lane == 0) red16[wv] = acc;
  __syncthreads();
  if (t == 0) {
    float s = 0.0f;
#pragma unroll
    for (int i = 0; i < 16; ++i) s += red16[i];
    bsum[bid] = s;
  }
}

__global__ __launch_bounds__(256) void chamfer_final(
    const float* __restrict__ bsum, float* __restrict__ out) {
  __shared__ float red4[4];
  const int t = threadIdx.x;
  float v = bsum[t];                       // 256 block sums
#pragma unroll
  for (int o = 32; o > 0; o >>= 1) v += __shfl_down(v, o, 64);
  const int lane = t & 63, wid = t >> 6;
  if (lane == 0) red4[wid] = v;
  __syncthreads();
  if (t == 0) out[0] = (red4[0] + red4[1]) + (red4[2] + red4[3]);
}

extern "C" void kernel_launch(void* const* d_in, const int* in_sizes, int n_in,
                              void* d_out, int out_size, void* d_ws, size_t ws_size,
                              hipStream_t stream) {
  const float* X = (const float*)d_in[0];
  const float* T = (const float*)d_in[1];
  float* out = (float*)d_out;
  float* bsum = (float*)d_ws;  // 256 floats, fully overwritten each launch

  chamfer_main<<<GRID_, 1024, 0, stream>>>(X, T, bsum);
  chamfer_final<<<1, 256, 0, stream>>>(bsum, out);
}

// Round 9
// 17.178 us; speedup vs baseline: 23.9103x; 1.4906x over previous
//
#include <hip/hip_runtime.h>

// Chamfer loss: B=8, V=4, N=2048, D=3 fp32.
// final = per_view[0] + sum_v per_view[v]; per_view = mean_b(cham_x + cham_y)
// => weight per (b,v,dir) job = ((v==0)?2:1)/8.
//
// R14 = R7 (proven best, 20.35us) with ONE change: the tail row-max.
// R7/R12/R13 all spent ~160 ds_swizzle + 160 fmax per wave on a 5-deep
// butterfly allreduce (328K LDS-unit ops chip-wide, serial chains at the
// kernel drain). Replaced by an LDS transpose-reduce in the dead yf buffer:
// scatter 32 acc values/lane into a per-wave [64][33]-f32 pane (stride 33 =>
// bank (row+col)%32, conflict-free both ways), xn2 in column 32, one
// barrier, lane l folds row l with 31 fmax in-register. 166 -> ~73 ds-ops
// per wave, no serial swizzle chains. Everything else byte-identical to R7.
//
// Math (absmax 0.0 across R7-R13): dot(x,y) via 4-term bf16 split inside
// mfma_f32_32x32x16_bf16; -0.5|y|^2 folded as fp32-accurate (wh,wl) K-slots
// vs A=1.0. t = x.y - 0.5|y|^2; min d2 <=> max t; d2 = |x|^2 - 2t (|x|^2 fp32).
// K-slot map (A,B share it): k0-2 h*h, k3-5 h*l, k6-8 l*h, k9-10 1*(wh,wl),
// k11-13 l*l, k14-15 zero. C layout: col=lane&31, row=(j&3)+8*(j>>2)+4*(lane>>5).

#define B_ 8
#define V_ 4
#define N_ 2048
#define JOBS 64
#define RPB 256                       // rows per block
#define GRID_ (JOBS * (N_ / RPB))     // 512
#define CHUNK 512                     // cols per LDS chunk
#define NCHUNK (N_ / CHUNK)           // 4
#define CPITCH 24                     // ushorts per col (48 B): 16 data + 8 pad

typedef short bf16x8 __attribute__((ext_vector_type(8)));
typedef float f32x16 __attribute__((ext_vector_type(16)));

__device__ __forceinline__ unsigned short f2bf(float f) {
  union { float f; unsigned u; } v; v.f = f;
  const unsigned r = v.u + 0x7fffu + ((v.u >> 16) & 1u);  // RNE, same as v_cvt
  return (unsigned short)(r >> 16);
}
__device__ __forceinline__ float bf2f(unsigned short h) {
  union { unsigned u; float f; } v; v.u = ((unsigned)h) << 16;
  return v.f;
}

__device__ __forceinline__ void pack_col(float y0, float y1, float y2,
                                         unsigned short* dst) {
  const unsigned short h0 = f2bf(y0), h1 = f2bf(y1), h2 = f2bf(y2);
  const unsigned short l0 = f2bf(y0 - bf2f(h0));
  const unsigned short l1 = f2bf(y1 - bf2f(h1));
  const unsigned short l2 = f2bf(y2 - bf2f(h2));
  const float w = -0.5f * fmaf(y0, y0, fmaf(y1, y1, y2 * y2));
  const unsigned short wh = f2bf(w);
  const unsigned short wl = f2bf(w - bf2f(wh));
  bf16x8 b0, b1;
  b0[0] = (short)h0; b0[1] = (short)h1; b0[2] = (short)h2;   // k0-2
  b0[3] = (short)l0; b0[4] = (short)l1; b0[5] = (short)l2;   // k3-5
  b0[6] = (short)h0; b0[7] = (short)h1;                      // k6-7
  b1[0] = (short)h2;                                         // k8
  b1[1] = (short)wh; b1[2] = (short)wl;                      // k9-10
  b1[3] = (short)l0; b1[4] = (short)l1; b1[5] = (short)l2;   // k11-13
  b1[6] = 0; b1[7] = 0;                                      // k14-15
  *(bf16x8*)(dst) = b0;        // ds_write_b128, 16B-aligned (pitch 48)
  *(bf16x8*)(dst + 8) = b1;
}

__device__ __forceinline__ void stage_chunk(const float* __restrict__ yb,
                                            unsigned short* __restrict__ dstbuf,
                                            int ch, int t) {
  const int c0 = ch * CHUNK + t * 2;                  // 2 cols per thread
  const float2* yp2 = (const float2*)(yb + (size_t)c0 * 3);  // 8B-aligned
  const float2 u0 = yp2[0], u1 = yp2[1], u2 = yp2[2];
  unsigned short* dst = dstbuf + (size_t)(t * 2) * CPITCH;
  pack_col(u0.x, u0.y, u1.x, dst);
  pack_col(u1.y, u2.x, u2.y, dst + CPITCH);
}

__global__ __launch_bounds__(256, 2) void chamfer_main(
    const float* __restrict__ X, const float* __restrict__ T,
    float* __restrict__ bsum) {
  __shared__ unsigned short yf[2][CHUNK * CPITCH];  // 2 x 24 KB
  __shared__ float red4[4];

  // XCD swizzle: physical p -> XCD p&7; XCD x owns logical [x*64,(x+1)*64)
  // = 8 consecutive jobs (y/x panels L2-resident per XCD).
  const int p = blockIdx.x;
  const int bid = (p & 7) * (GRID_ / 8) + (p >> 3);
  const int job = bid >> 3;          // [0,64): 8 blocks per job
  const int rc  = bid & 7;           // row-chunk of 256
  const int pair = job >> 1;
  const int dir  = job & 1;          // 0: rows=X cols=T (cham_x), 1: swapped
  const float* xb = (dir ? T : X) + (size_t)pair * N_ * 3;
  const float* yb = (dir ? X : T) + (size_t)pair * N_ * 3;
  const int t = threadIdx.x;
  const int lane = t & 63;
  const int wv = t >> 6;
  const int lr = lane & 31;          // A-row / B-col within tile
  const int g  = lane >> 5;          // K-group (which 8 k-slots this lane feeds)

  // ---- A fragments: this wave's 64 rows = 2 row-tiles of 32 ----
  bf16x8 afrag[2];
  float xn2[2];
  const int rbase = rc * RPB + wv * 64;
#pragma unroll
  for (int rt = 0; rt < 2; ++rt) {
    const int r = rbase + rt * 32 + lr;
    const float x0 = xb[r * 3 + 0], x1 = xb[r * 3 + 1], x2 = xb[r * 3 + 2];
    xn2[rt] = fmaf(x0, x0, fmaf(x1, x1, x2 * x2));
    const unsigned short h0 = f2bf(x0), h1 = f2bf(x1), h2 = f2bf(x2);
    const unsigned short l0 = f2bf(x0 - bf2f(h0));
    const unsigned short l1 = f2bf(x1 - bf2f(h1));
    const unsigned short l2 = f2bf(x2 - bf2f(h2));
    const unsigned short ONE = 0x3F80;  // bf16 1.0
    bf16x8 a;
    if (g == 0) {  // k0-7
      a[0] = (short)h0; a[1] = (short)h1; a[2] = (short)h2;
      a[3] = (short)h0; a[4] = (short)h1; a[5] = (short)h2;
      a[6] = (short)l0; a[7] = (short)l1;
    } else {       // k8-15
      a[0] = (short)l2; a[1] = (short)ONE; a[2] = (short)ONE;
      a[3] = (short)l0; a[4] = (short)l1; a[5] = (short)l2;
      a[6] = 0; a[7] = 0;
    }
    afrag[rt] = a;
  }

  f32x16 r0, r1;
#pragma unroll
  for (int j = 0; j < 16; ++j) { r0[j] = -1e30f; r1[j] = -1e30f; }

  stage_chunk(yb, yf[0], 0, t);
  __syncthreads();

  for (int ch = 0; ch < NCHUNK; ++ch) {
    if (ch + 1 < NCHUNK)                       // overlap: fill other buffer
      stage_chunk(yb, yf[(ch + 1) & 1], ch + 1, t);
    const unsigned short* yfb = yf[ch & 1];
#pragma unroll
    for (int pr = 0; pr < CHUNK / 64; ++pr) {  // 8 col-tile pairs
      const unsigned short* pa = yfb + (size_t)(pr * 64 + lr) * CPITCH + g * 8;
      const bf16x8 bA = *(const bf16x8*)pa;                    // ds_read_b128
      const bf16x8 bB = *(const bf16x8*)(pa + 32 * CPITCH);
      const f32x16 d00 =
          __builtin_amdgcn_mfma_f32_32x32x16_bf16(afrag[0], bA, (f32x16){}, 0, 0, 0);
      const f32x16 d10 =
          __builtin_amdgcn_mfma_f32_32x32x16_bf16(afrag[1], bA, (f32x16){}, 0, 0, 0);
      const f32x16 d01 =
          __builtin_amdgcn_mfma_f32_32x32x16_bf16(afrag[0], bB, (f32x16){}, 0, 0, 0);
      const f32x16 d11 =
          __builtin_amdgcn_mfma_f32_32x32x16_bf16(afrag[1], bB, (f32x16){}, 0, 0, 0);
#pragma unroll
      for (int j = 0; j < 16; ++j) {           // 2 new values per v_max3
        r0[j] = fmaxf(fmaxf(r0[j], d00[j]), d01[j]);
        r1[j] = fmaxf(fmaxf(r1[j], d10[j]), d11[j]);
      }
    }
    __syncthreads();  // writes for ch+1 visible; reads of ch done before reuse
  }

  // ---- tail (NEW vs R7): LDS transpose-reduce instead of 160-swizzle
  // butterfly. yf is dead (barrier above). Per-wave pane [64 rows][33 f32]:
  // value (rt,j) of lane -> row rt*32+(j&3)+8*(j>>2)+4*g, col lr.
  // Bank = (row*33 + col)%32 = (row+col)%32: conflict-free writes AND reads.
  // Column 32 holds |x|^2 per row. One barrier, then lane l folds row l.
  float* tw = ((float*)&yf[0][0]) + wv * (64 * 33);  // 8448 B/wave, 33.8 KB tot
#pragma unroll
  for (int rt = 0; rt < 2; ++rt) {
#pragma unroll
    for (int j = 0; j < 16; ++j) {
      const int rl = rt * 32 + (j & 3) + 8 * (j >> 2) + 4 * g;
      tw[rl * 33 + lr] = rt ? r1[j] : r0[j];
    }
    // lanes l and l+32 share lr -> same row, same xn2 value: benign dup write
    tw[(rt * 32 + lr) * 33 + 32] = xn2[rt];
  }
  __syncthreads();

  // lane l owns row l of its wave's pane: fold 32 col-maxes + xn2.
  float mx = -1e30f;
#pragma unroll
  for (int c = 0; c < 32; ++c) mx = fmaxf(mx, tw[lane * 33 + c]);
  const float d = fmaf(-2.0f, mx, tw[lane * 33 + 32]);  // min d2 for row

  const int v_ = pair & (V_ - 1);
  float acc = d * (((v_ == 0) ? 2.0f : 1.0f) * (1.0f / (float)B_));
#pragma unroll
  for (int o = 32; o > 0; o >>= 1) acc += __shfl_down(acc, o, 64);
  if (lane == 0) red4[wv] = acc;
  __syncthreads();
  if (t == 0) bsum[bid] = (red4[0] + red4[1]) + (red4[2] + red4[3]);
}

__global__ __launch_bounds__(256) void chamfer_final(
    const float* __restrict__ bsum, float* __restrict__ out) {
  __shared__ float red4[4];
  const int t = threadIdx.x;
  float v = bsum[t] + bsum[t + 256];
#pragma unroll
  for (int o = 32; o > 0; o >>= 1) v += __shfl_down(v, o, 64);
  const int lane = t & 63, wid = t >> 6;
  if (lane == 0) red4[wid] = v;
  __syncthreads();
  if (t == 0) out[0] = (red4[0] + red4[1]) + (red4[2] + red4[3]);
}

extern "C" void kernel_launch(void* const* d_in, const int* in_sizes, int n_in,
                              void* d_out, int out_size, void* d_ws, size_t ws_size,
                              hipStream_t stream) {
  const float* X = (const float*)d_in[0];
  const float* T = (const float*)d_in[1];
  float* out = (float*)d_out;
  float* bsum = (float*)d_ws;  // 512 floats, fully overwritten each launch

  chamfer_main<<<GRID_, 256, 0, stream>>>(X, T, bsum);
  chamfer_final<<<1, 256, 0, stream>>>(bsum, out);
}